// Round 2
// baseline (466.103 us; speedup 1.0000x reference)
//
#include <hip/hip_runtime.h>

#define EMB 128

typedef __attribute__((ext_vector_type(8))) short short8;
typedef __attribute__((ext_vector_type(4))) short short4v;
typedef __attribute__((ext_vector_type(4))) float floatx4;

#define MFMA(a, b, c) __builtin_amdgcn_mfma_f32_16x16x32_bf16((a), (b), (c), 0, 0, 0)

__device__ __forceinline__ ushort f2b(float f) {
    unsigned u = __float_as_uint(f);
    return (ushort)((u + 0x7fff + ((u >> 16) & 1)) >> 16);   // RNE
}
__device__ __forceinline__ float b2f(ushort h) {
    return __uint_as_float(((unsigned)h) << 16);
}
__device__ __forceinline__ short8 cvt8(const float* p) {
    float4 f0 = *(const float4*)p;
    float4 f1 = *(const float4*)(p + 4);
    short8 v;
    v[0] = f2b(f0.x); v[1] = f2b(f0.y); v[2] = f2b(f0.z); v[3] = f2b(f0.w);
    v[4] = f2b(f1.x); v[5] = f2b(f1.y); v[6] = f2b(f1.z); v[7] = f2b(f1.w);
    return v;
}

// ---------------------------------------------------------------------------
// fused independent pre-work: blocks [0,384) convert the 5 weight matrices to
// bf16; blocks [384, 384+eb) histogram right indices.
__global__ __launch_bounds__(256) void k_cvthist(const float* __restrict__ w0,
                                                 const float* __restrict__ w1,
                                                 const float* __restrict__ w2,
                                                 const float* __restrict__ w3,
                                                 const float* __restrict__ w4,
                                                 ushort* __restrict__ dst,
                                                 const int* __restrict__ eidx,
                                                 int* __restrict__ cnt,
                                                 int n_edges) {
    int bid = blockIdx.x;
    if (bid < 384) {
        int i = bid * 256 + threadIdx.x;     // 0..98303
        const float* src; int off;
        if (i < 16384)      { src = w0; off = i; }
        else if (i < 32768) { src = w1; off = i - 16384; }
        else if (i < 49152) { src = w2; off = i - 32768; }
        else if (i < 81920) { src = w3; off = i - 49152; }
        else                { src = w4; off = i - 81920; }
        dst[i] = f2b(src[off]);
    } else {
        int e = (bid - 384) * 256 + threadIdx.x;
        if (e < n_edges) atomicAdd(&cnt[eidx[n_edges + e]], 1);
    }
}

#define SCAN_CHUNK 4096
__global__ __launch_bounds__(1024) void k_scan1(const int* __restrict__ cnt,
                                                int* __restrict__ offs,
                                                int* __restrict__ bsum, int n) {
    __shared__ int buf[1024];
    int t = threadIdx.x;
    int i0 = blockIdx.x * SCAN_CHUNK + t * 4;
    int v[4];
#pragma unroll
    for (int u = 0; u < 4; u++) { int i = i0 + u; v[u] = (i < n) ? cnt[i] : 0; }
    int s = v[0] + v[1] + v[2] + v[3];
    buf[t] = s;
    __syncthreads();
    for (int d = 1; d < 1024; d <<= 1) {
        int x = (t >= d) ? buf[t - d] : 0;
        __syncthreads();
        buf[t] += x;
        __syncthreads();
    }
    int excl = buf[t] - s;
#pragma unroll
    for (int u = 0; u < 4; u++) { int i = i0 + u; if (i < n) offs[i] = excl; excl += v[u]; }
    if (t == 1023) bsum[blockIdx.x] = buf[1023];
}

__global__ __launch_bounds__(1024) void k_scan2(const int* __restrict__ bsum,
                                                int* __restrict__ offs,
                                                int* __restrict__ cursor, int n) {
    int bid = blockIdx.x;
    int base = 0;
    for (int j = 0; j < bid; j++) base += bsum[j];
    int i0 = bid * SCAN_CHUNK + threadIdx.x * 4;
#pragma unroll
    for (int u = 0; u < 4; u++) {
        int i = i0 + u;
        if (i < n) { int o = offs[i] + base; offs[i] = o; cursor[i] = o; }
    }
}

// ---------------------------------------------------------------------------
// fused: blocks [0,eb) -> perm (sorted (li,ef) list); [eb, eb+nblk) -> left
// projection; [eb+nblk, eb+2*nblk) -> right projection.
//
// Projection uses SWAPPED MFMA operands: MFMA(W_frag, X_frag) makes the D
// fragment hold 4 CONSECUTIVE output columns of one X-row per lane
// (row=(lane>>4)*4+r -> W row = out col; col=lane&15 -> X row). Each wave
// owns 16 rows x all 128 cols: every X row is read exactly once per block
// (old layout read each row twice) and each store is an 8B ushort4 instead
// of 4 scattered 2B stores.
__global__ __launch_bounds__(256) void k_permproj(const int* __restrict__ eidx,
                                                  const float* __restrict__ ef,
                                                  int* __restrict__ cursor,
                                                  int2* __restrict__ sle,
                                                  int n_edges,
                                                  const float* __restrict__ XL,
                                                  const float* __restrict__ XR,
                                                  const ushort* __restrict__ WLb,
                                                  const ushort* __restrict__ WRb,
                                                  const float* __restrict__ bias,
                                                  ushort* __restrict__ YL,
                                                  ushort* __restrict__ YR,
                                                  int n, int eb, int nblk) {
    int bid = blockIdx.x;
    if (bid < eb) {
        int e = bid * 256 + threadIdx.x;
        if (e < n_edges) {
            int r = eidx[n_edges + e];
            int p = atomicAdd(&cursor[r], 1);
            int2 v; v.x = eidx[e]; v.y = __float_as_int(ef[e]);
            sle[p] = v;
        }
        return;
    }
    bid -= eb;
    const float* X; const ushort* Wb; ushort* Y; int has_bias;
    if (bid < nblk) { X = XL; Wb = WLb; Y = YL; has_bias = 1; }
    else            { X = XR; Wb = WRb; Y = YR; has_bias = 0; bid -= nblk; }

    int t = threadIdx.x, wave = t >> 6, lane = t & 63;
    int m = lane & 15, quad = lane >> 4;
    size_t row0 = (size_t)bid * 64;
    size_t row = row0 + wave * 16 + m;
    size_t rowc = (row < (size_t)n) ? row : (size_t)(n - 1);

    // X fragment (B operand): lane m -> row, quad -> k offset; read ONCE.
    short8 xf[4];
    const float* xr = X + rowc * EMB;
#pragma unroll
    for (int ks = 0; ks < 4; ks++)
        xf[ks] = cvt8(xr + ks * 32 + quad * 8);

    bool ok = (row < (size_t)n);
#pragma unroll
    for (int wt = 0; wt < 8; wt++) {
        floatx4 acc = {0.f, 0.f, 0.f, 0.f};
#pragma unroll
        for (int ks = 0; ks < 4; ks++) {
            short8 w = *(const short8*)(Wb + (size_t)(wt * 16 + m) * EMB + ks * 32 + quad * 8);
            acc = MFMA(w, xf[ks], acc);
        }
        float b0 = 0.f, b1_ = 0.f, b2_ = 0.f, b3 = 0.f;
        if (has_bias) {
            float4 bb = *(const float4*)(bias + wt * 16 + quad * 4);
            b0 = bb.x; b1_ = bb.y; b2_ = bb.z; b3 = bb.w;
        }
        if (ok) {
            short4v o;
            o[0] = f2b(acc[0] + b0);
            o[1] = f2b(acc[1] + b1_);
            o[2] = f2b(acc[2] + b2_);
            o[3] = f2b(acc[3] + b3);
            *(short4v*)(Y + row * EMB + wt * 16 + quad * 4) = o;
        }
    }
}

// ---------------------------------------------------------------------------
// FUSED segmented reduction + conv GEMM + output MLP.  Block = 64 right rows,
// 4 waves. Wave w reduces rows [w*16, w*16+16) into LDS (S tile), then runs
// all three GEMM phases for those same rows with swapped MFMA operands.
// Every LDS row is produced and consumed by the SAME wave -> no barriers;
// waves drain independently (better under degree imbalance). Final stores
// are coalesced float4. Saves the 51 MB S global round trip + one launch.
__global__ __launch_bounds__(256) void k_redout(const ushort* __restrict__ Pl,
                                                const ushort* __restrict__ Pr,
                                                const int2* __restrict__ sle,
                                                const float* __restrict__ We,
                                                const int* __restrict__ offs,
                                                const float* __restrict__ scale_final,
                                                const float* __restrict__ right,
                                                const ushort* __restrict__ Wfb,
                                                const float* __restrict__ bf,
                                                const float* __restrict__ sc_post,
                                                const ushort* __restrict__ W1b,
                                                const float* __restrict__ b1,
                                                const ushort* __restrict__ W2b,
                                                const float* __restrict__ b2,
                                                float* __restrict__ out,
                                                int n, int n_edges) {
    __shared__ ushort H[64][136];
    __shared__ float degs[64];
    int t = threadIdx.x, wave = t >> 6, lane = t & 63;
    int m = lane & 15, quad = lane >> 4;
    size_t row0 = (size_t)blockIdx.x * 64;
    float scale = scale_final[0];
    float sp = sc_post[0];
    float2 we = *(const float2*)(We + lane * 2);

    // ---- phase 0: segmented reduction, 16 rows per wave, into LDS ----
    for (int i = 0; i < 16; i++) {
        int rl = wave * 16 + i;
        size_t r = row0 + rl;
        float ax = 0.f, ay = 0.f;
        int dg = 0;
        if (r < (size_t)n) {
            ushort2 pru = *(const ushort2*)(Pr + r * EMB + lane * 2);
            float prx = b2f(pru.x), pry = b2f(pru.y);
            int s0 = offs[r];
            int s1 = (r + 1 < (size_t)n) ? offs[r + 1] : n_edges;
            dg = s1 - s0;
            int ei = s0;
            for (; ei + 4 <= s1; ei += 4) {
                int2 e0 = sle[ei], e1 = sle[ei + 1], e2 = sle[ei + 2], e3 = sle[ei + 3];
                ushort2 p0 = *(const ushort2*)(Pl + (size_t)e0.x * EMB + lane * 2);
                ushort2 p1 = *(const ushort2*)(Pl + (size_t)e1.x * EMB + lane * 2);
                ushort2 p2 = *(const ushort2*)(Pl + (size_t)e2.x * EMB + lane * 2);
                ushort2 p3 = *(const ushort2*)(Pl + (size_t)e3.x * EMB + lane * 2);
                float f0 = __int_as_float(e0.y), f1 = __int_as_float(e1.y);
                float f2_ = __int_as_float(e2.y), f3 = __int_as_float(e3.y);
                ax += fmaxf((b2f(p0.x) + prx + f0 * we.x) * scale, 0.f);
                ay += fmaxf((b2f(p0.y) + pry + f0 * we.y) * scale, 0.f);
                ax += fmaxf((b2f(p1.x) + prx + f1 * we.x) * scale, 0.f);
                ay += fmaxf((b2f(p1.y) + pry + f1 * we.y) * scale, 0.f);
                ax += fmaxf((b2f(p2.x) + prx + f2_ * we.x) * scale, 0.f);
                ay += fmaxf((b2f(p2.y) + pry + f2_ * we.y) * scale, 0.f);
                ax += fmaxf((b2f(p3.x) + prx + f3 * we.x) * scale, 0.f);
                ay += fmaxf((b2f(p3.y) + pry + f3 * we.y) * scale, 0.f);
            }
            for (; ei < s1; ei++) {
                int2 e0 = sle[ei];
                ushort2 p0 = *(const ushort2*)(Pl + (size_t)e0.x * EMB + lane * 2);
                float f0 = __int_as_float(e0.y);
                ax += fmaxf((b2f(p0.x) + prx + f0 * we.x) * scale, 0.f);
                ay += fmaxf((b2f(p0.y) + pry + f0 * we.y) * scale, 0.f);
            }
        }
        ushort2 o; o.x = f2b(ax); o.y = f2b(ay);
        *(ushort2*)(&H[rl][lane * 2]) = o;
        if (lane == 0) degs[rl] = (float)dg;
    }
    // No __syncthreads: all H/degs rows below are read by the wave that
    // wrote them (rl = wave*16 + m), ordered by per-wave lgkmcnt.

    int rl = wave * 16 + m;
    size_t xrow = row0 + rl;
    size_t xrowc = (xrow < (size_t)n) ? xrow : (size_t)(n - 1);
    bool ok = (xrow < (size_t)n);
    float dd = degs[rl];

    // S fragments (B operand) + right fragments (for concat half of W1)
    short8 s4[4], ar[4];
    const float* rr = right + xrowc * EMB;
#pragma unroll
    for (int ks = 0; ks < 4; ks++) {
        s4[ks] = *(const short8*)(&H[rl][ks * 32 + quad * 8]);
        ar[ks] = cvt8(rr + ks * 32 + quad * 8);
    }

    // ---- phase 1: conv = (S @ Wf^T + deg*bf) * sp -> H (own rows) ----
#pragma unroll
    for (int wt = 0; wt < 8; wt++) {
        floatx4 acc = {0.f, 0.f, 0.f, 0.f};
#pragma unroll
        for (int ks = 0; ks < 4; ks++) {
            short8 w = *(const short8*)(Wfb + (size_t)(wt * 16 + m) * EMB + ks * 32 + quad * 8);
            acc = MFMA(w, s4[ks], acc);
        }
        float4 bb = *(const float4*)(bf + wt * 16 + quad * 4);
        short4v o;
        o[0] = f2b((acc[0] + dd * bb.x) * sp);
        o[1] = f2b((acc[1] + dd * bb.y) * sp);
        o[2] = f2b((acc[2] + dd * bb.z) * sp);
        o[3] = f2b((acc[3] + dd * bb.w) * sp);
        *(short4v*)(&H[rl][wt * 16 + quad * 4]) = o;
    }

    // ---- phase 2: hidden = relu([conv ; right] @ W1^T + b1) -> H ----
    short8 c4[4];
#pragma unroll
    for (int ks = 0; ks < 4; ks++)
        c4[ks] = *(const short8*)(&H[rl][ks * 32 + quad * 8]);
#pragma unroll
    for (int wt = 0; wt < 8; wt++) {
        floatx4 acc = {0.f, 0.f, 0.f, 0.f};
        const ushort* wrow = W1b + (size_t)(wt * 16 + m) * 256;
#pragma unroll
        for (int ks = 0; ks < 4; ks++) {
            short8 w = *(const short8*)(wrow + ks * 32 + quad * 8);
            acc = MFMA(w, c4[ks], acc);
        }
#pragma unroll
        for (int ks = 0; ks < 4; ks++) {
            short8 w = *(const short8*)(wrow + 128 + ks * 32 + quad * 8);
            acc = MFMA(w, ar[ks], acc);
        }
        float4 bb = *(const float4*)(b1 + wt * 16 + quad * 4);
        short4v o;
        o[0] = f2b(fmaxf(acc[0] + bb.x, 0.f));
        o[1] = f2b(fmaxf(acc[1] + bb.y, 0.f));
        o[2] = f2b(fmaxf(acc[2] + bb.z, 0.f));
        o[3] = f2b(fmaxf(acc[3] + bb.w, 0.f));
        *(short4v*)(&H[rl][wt * 16 + quad * 4]) = o;
    }

    // ---- phase 3: out = hidden @ W2^T + b2 (coalesced float4 stores) ----
    short8 h4[4];
#pragma unroll
    for (int ks = 0; ks < 4; ks++)
        h4[ks] = *(const short8*)(&H[rl][ks * 32 + quad * 8]);
#pragma unroll
    for (int wt = 0; wt < 8; wt++) {
        floatx4 acc = {0.f, 0.f, 0.f, 0.f};
#pragma unroll
        for (int ks = 0; ks < 4; ks++) {
            short8 w = *(const short8*)(W2b + (size_t)(wt * 16 + m) * EMB + ks * 32 + quad * 8);
            acc = MFMA(w, h4[ks], acc);
        }
        if (ok) {
            float4 bb = *(const float4*)(b2 + wt * 16 + quad * 4);
            float4 o;
            o.x = acc[0] + bb.x;
            o.y = acc[1] + bb.y;
            o.z = acc[2] + bb.z;
            o.w = acc[3] + bb.w;
            *(float4*)(out + xrow * EMB + wt * 16 + quad * 4) = o;
        }
    }
}

// ---------------------------------------------------------------------------
extern "C" void kernel_launch(void* const* d_in, const int* in_sizes, int n_in,
                              void* d_out, int out_size, void* d_ws, size_t ws_size,
                              hipStream_t stream) {
    const float* left   = (const float*)d_in[0];
    const int*   eidx   = (const int*)  d_in[1];
    const float* efeat  = (const float*)d_in[2];
    const float* right  = (const float*)d_in[3];
    const float* W_left = (const float*)d_in[5];
    const float* b_left = (const float*)d_in[6];
    const float* W_edge = (const float*)d_in[7];
    const float* W_right= (const float*)d_in[8];
    const float* sc_fin = (const float*)d_in[9];
    const float* W_fin  = (const float*)d_in[10];
    const float* b_fin  = (const float*)d_in[11];
    const float* sc_post= (const float*)d_in[12];
    const float* W_out1 = (const float*)d_in[13];
    const float* b_out1 = (const float*)d_in[14];
    const float* W_out2 = (const float*)d_in[15];
    const float* b_out2 = (const float*)d_in[16];

    int n_left  = in_sizes[0] / EMB;        // 100000
    int n_edges = in_sizes[2];              // 600000
    int n_right = in_sizes[3] / EMB;        // 100000

    ushort* us = (ushort*)d_ws;
    ushort* Wl_b = us;                       // packed bf16 weights
    ushort* Wr_b = us + 16384;
    ushort* Wf_b = us + 32768;
    ushort* W1_b = us + 49152;
    ushort* W2_b = us + 81920;
    ushort* Pl   = us + 98304;               // n_left*128
    ushort* Pr   = Pl + (size_t)n_left * EMB;
    ushort* S    = Pr + (size_t)n_right * EMB;   // unused now (layout kept)
    int* cnt    = (int*)(S + (size_t)n_right * EMB);
    int* offs   = cnt + n_right;
    int* cursor = offs + n_right;
    int* bsum   = cursor + n_right;
    int2* sle   = (int2*)(bsum + 64);

    hipMemsetAsync(cnt, 0, (size_t)n_right * sizeof(int), stream);

    int eb = (n_edges + 255) / 256;          // 2344
    int nblk = (n_left + 63) / 64;           // 1563

    // weights->bf16 + degree histogram (independent, one launch)
    k_cvthist<<<384 + eb, 256, 0, stream>>>(W_left, W_right, W_fin, W_out1,
                                            W_out2, us, eidx, cnt, n_edges);

    // exclusive scan of degrees
    int nsb = (n_right + SCAN_CHUNK - 1) / SCAN_CHUNK;   // 25
    k_scan1<<<nsb, 1024, 0, stream>>>(cnt, offs, bsum, n_right);
    k_scan2<<<nsb, 1024, 0, stream>>>(bsum, offs, cursor, n_right);

    // sorted edge list + both projections (independent, one launch)
    k_permproj<<<eb + 2 * nblk, 256, 0, stream>>>(eidx, efeat, cursor, sle,
                                                  n_edges, left, right,
                                                  Wl_b, Wr_b, b_left,
                                                  Pl, Pr, n_left, eb, nblk);

    // fused segmented reduction + conv GEMM + output MLP
    k_redout<<<(n_right + 63) / 64, 256, 0, stream>>>(Pl, Pr, sle, W_edge, offs,
                                                      sc_fin, right, Wf_b, b_fin,
                                                      sc_post, W1_b, b_out1,
                                                      W2_b, b_out2,
                                                      (float*)d_out,
                                                      n_right, n_edges);
}

// Round 3
// 430.120 us; speedup vs baseline: 1.0837x; 1.0837x over previous
//
#include <hip/hip_runtime.h>

#define EMB 128

typedef __attribute__((ext_vector_type(8))) short short8;
typedef __attribute__((ext_vector_type(4))) short short4v;
typedef __attribute__((ext_vector_type(4))) float floatx4;

#define MFMA(a, b, c) __builtin_amdgcn_mfma_f32_16x16x32_bf16((a), (b), (c), 0, 0, 0)

__device__ __forceinline__ ushort f2b(float f) {
    unsigned u = __float_as_uint(f);
    return (ushort)((u + 0x7fff + ((u >> 16) & 1)) >> 16);   // RNE
}
__device__ __forceinline__ float b2f(ushort h) {
    return __uint_as_float(((unsigned)h) << 16);
}
__device__ __forceinline__ short8 cvt8(const float* p) {
    float4 f0 = *(const float4*)p;
    float4 f1 = *(const float4*)(p + 4);
    short8 v;
    v[0] = f2b(f0.x); v[1] = f2b(f0.y); v[2] = f2b(f0.z); v[3] = f2b(f0.w);
    v[4] = f2b(f1.x); v[5] = f2b(f1.y); v[6] = f2b(f1.z); v[7] = f2b(f1.w);
    return v;
}

// ---------------------------------------------------------------------------
// fused independent pre-work: blocks [0,384) convert the 5 weight matrices to
// bf16; blocks [384, 384+eb) histogram right indices.
__global__ __launch_bounds__(256) void k_cvthist(const float* __restrict__ w0,
                                                 const float* __restrict__ w1,
                                                 const float* __restrict__ w2,
                                                 const float* __restrict__ w3,
                                                 const float* __restrict__ w4,
                                                 ushort* __restrict__ dst,
                                                 const int* __restrict__ eidx,
                                                 int* __restrict__ cnt,
                                                 int n_edges) {
    int bid = blockIdx.x;
    if (bid < 384) {
        int i = bid * 256 + threadIdx.x;     // 0..98303
        const float* src; int off;
        if (i < 16384)      { src = w0; off = i; }
        else if (i < 32768) { src = w1; off = i - 16384; }
        else if (i < 49152) { src = w2; off = i - 32768; }
        else if (i < 81920) { src = w3; off = i - 49152; }
        else                { src = w4; off = i - 81920; }
        dst[i] = f2b(src[off]);
    } else {
        int e = (bid - 384) * 256 + threadIdx.x;
        if (e < n_edges) atomicAdd(&cnt[eidx[n_edges + e]], 1);
    }
}

#define SCAN_CHUNK 4096
__global__ __launch_bounds__(1024) void k_scan1(const int* __restrict__ cnt,
                                                int* __restrict__ offs,
                                                int* __restrict__ bsum, int n) {
    __shared__ int buf[1024];
    int t = threadIdx.x;
    int i0 = blockIdx.x * SCAN_CHUNK + t * 4;
    int v[4];
#pragma unroll
    for (int u = 0; u < 4; u++) { int i = i0 + u; v[u] = (i < n) ? cnt[i] : 0; }
    int s = v[0] + v[1] + v[2] + v[3];
    buf[t] = s;
    __syncthreads();
    for (int d = 1; d < 1024; d <<= 1) {
        int x = (t >= d) ? buf[t - d] : 0;
        __syncthreads();
        buf[t] += x;
        __syncthreads();
    }
    int excl = buf[t] - s;
#pragma unroll
    for (int u = 0; u < 4; u++) { int i = i0 + u; if (i < n) offs[i] = excl; excl += v[u]; }
    if (t == 1023) bsum[blockIdx.x] = buf[1023];
}

__global__ __launch_bounds__(1024) void k_scan2(const int* __restrict__ bsum,
                                                int* __restrict__ offs,
                                                int* __restrict__ cursor, int n) {
    int bid = blockIdx.x;
    int base = 0;
    for (int j = 0; j < bid; j++) base += bsum[j];
    int i0 = bid * SCAN_CHUNK + threadIdx.x * 4;
#pragma unroll
    for (int u = 0; u < 4; u++) {
        int i = i0 + u;
        if (i < n) { int o = offs[i] + base; offs[i] = o; cursor[i] = o; }
    }
}

// ---------------------------------------------------------------------------
// fused: blocks [0,eb) -> perm (sorted (li,ef) list); [eb, eb+nblk) -> left
// projection; [eb+nblk, eb+2*nblk) -> right projection.
// Swapped MFMA operands: each wave owns 16 rows x all 128 cols; X read once;
// 8B coalesced ushort4 stores.
__global__ __launch_bounds__(256) void k_permproj(const int* __restrict__ eidx,
                                                  const float* __restrict__ ef,
                                                  int* __restrict__ cursor,
                                                  int2* __restrict__ sle,
                                                  int n_edges,
                                                  const float* __restrict__ XL,
                                                  const float* __restrict__ XR,
                                                  const ushort* __restrict__ WLb,
                                                  const ushort* __restrict__ WRb,
                                                  const float* __restrict__ bias,
                                                  ushort* __restrict__ YL,
                                                  ushort* __restrict__ YR,
                                                  int n, int eb, int nblk) {
    int bid = blockIdx.x;
    if (bid < eb) {
        int e = bid * 256 + threadIdx.x;
        if (e < n_edges) {
            int r = eidx[n_edges + e];
            int p = atomicAdd(&cursor[r], 1);
            int2 v; v.x = eidx[e]; v.y = __float_as_int(ef[e]);
            sle[p] = v;
        }
        return;
    }
    bid -= eb;
    const float* X; const ushort* Wb; ushort* Y; int has_bias;
    if (bid < nblk) { X = XL; Wb = WLb; Y = YL; has_bias = 1; }
    else            { X = XR; Wb = WRb; Y = YR; has_bias = 0; bid -= nblk; }

    int t = threadIdx.x, wave = t >> 6, lane = t & 63;
    int m = lane & 15, quad = lane >> 4;
    size_t row0 = (size_t)bid * 64;
    size_t row = row0 + wave * 16 + m;
    size_t rowc = (row < (size_t)n) ? row : (size_t)(n - 1);

    short8 xf[4];
    const float* xr = X + rowc * EMB;
#pragma unroll
    for (int ks = 0; ks < 4; ks++)
        xf[ks] = cvt8(xr + ks * 32 + quad * 8);

    bool ok = (row < (size_t)n);
#pragma unroll
    for (int wt = 0; wt < 8; wt++) {
        floatx4 acc = {0.f, 0.f, 0.f, 0.f};
#pragma unroll
        for (int ks = 0; ks < 4; ks++) {
            short8 w = *(const short8*)(Wb + (size_t)(wt * 16 + m) * EMB + ks * 32 + quad * 8);
            acc = MFMA(w, xf[ks], acc);
        }
        float b0 = 0.f, b1_ = 0.f, b2_ = 0.f, b3 = 0.f;
        if (has_bias) {
            float4 bb = *(const float4*)(bias + wt * 16 + quad * 4);
            b0 = bb.x; b1_ = bb.y; b2_ = bb.z; b3 = bb.w;
        }
        if (ok) {
            short4v o;
            o[0] = f2b(acc[0] + b0);
            o[1] = f2b(acc[1] + b1_);
            o[2] = f2b(acc[2] + b2_);
            o[3] = f2b(acc[3] + b3);
            *(short4v*)(Y + row * EMB + wt * 16 + quad * 4) = o;
        }
    }
}

// ---------------------------------------------------------------------------
// segmented reduction: S[r] = sum_e relu(scale*(Pl[l]+Pr[r]+ef*We)), bf16 out.
// ONE WAVE PER RIGHT NODE (100k waves for max memory-level parallelism).
// The wave splits into 4 edge-groups of 16 lanes; each lane covers 8 columns
// via 16B ushort8 loads. One dependency round = 4 edges; unroll x2 = 8
// gathers in flight. Cross-group combine: 16 shfl_xor at the end.
__global__ __launch_bounds__(256) void k_reduce(const ushort* __restrict__ Pl,
                                                const ushort* __restrict__ Pr,
                                                const int2* __restrict__ sle,
                                                const float* __restrict__ We,
                                                const int* __restrict__ offs,
                                                const float* __restrict__ scale_final,
                                                ushort* __restrict__ S,
                                                int n_right, int n_edges) {
    int r = blockIdx.x * 4 + (threadIdx.x >> 6);
    if (r >= n_right) return;
    int lane = threadIdx.x & 63;
    int g = lane >> 4;          // edge group 0..3
    int m = lane & 15;          // column group: cols [m*8, m*8+8)
    float scale = scale_final[0];

    float4 w0 = *(const float4*)(We + m * 8);
    float4 w1 = *(const float4*)(We + m * 8 + 4);
    short8 prv = *(const short8*)(Pr + (size_t)r * EMB + m * 8);
    float we[8], pr[8];
    we[0] = w0.x; we[1] = w0.y; we[2] = w0.z; we[3] = w0.w;
    we[4] = w1.x; we[5] = w1.y; we[6] = w1.z; we[7] = w1.w;
#pragma unroll
    for (int j = 0; j < 8; j++) pr[j] = b2f((ushort)prv[j]);

    float acc[8] = {0.f, 0.f, 0.f, 0.f, 0.f, 0.f, 0.f, 0.f};
    int s0 = offs[r];
    int s1 = (r + 1 < n_right) ? offs[r + 1] : n_edges;
    int e = s0 + g;
    for (; e + 4 < s1; e += 8) {       // two edges per group in flight
        int2 ea = sle[e];
        int2 eb = sle[e + 4];
        short8 pa = *(const short8*)(Pl + (size_t)ea.x * EMB + m * 8);
        short8 pb = *(const short8*)(Pl + (size_t)eb.x * EMB + m * 8);
        float fa = __int_as_float(ea.y), fb = __int_as_float(eb.y);
#pragma unroll
        for (int j = 0; j < 8; j++) {
            acc[j] += fmaxf((b2f((ushort)pa[j]) + pr[j] + fa * we[j]) * scale, 0.f);
            acc[j] += fmaxf((b2f((ushort)pb[j]) + pr[j] + fb * we[j]) * scale, 0.f);
        }
    }
    if (e < s1) {                      // at most one leftover per group
        int2 ea = sle[e];
        short8 pa = *(const short8*)(Pl + (size_t)ea.x * EMB + m * 8);
        float fa = __int_as_float(ea.y);
#pragma unroll
        for (int j = 0; j < 8; j++)
            acc[j] += fmaxf((b2f((ushort)pa[j]) + pr[j] + fa * we[j]) * scale, 0.f);
    }
    // sum the 4 edge-groups (lanes differing in bits 4 and 5)
#pragma unroll
    for (int j = 0; j < 8; j++) {
        acc[j] += __shfl_xor(acc[j], 16);
        acc[j] += __shfl_xor(acc[j], 32);
    }
    if (g == 0) {
        short8 o;
#pragma unroll
        for (int j = 0; j < 8; j++) o[j] = f2b(acc[j]);
        *(short8*)(S + (size_t)r * EMB + m * 8) = o;
    }
}

// ---------------------------------------------------------------------------
// conv GEMM + output MLP (swapped MFMA operands).  Block = 64 rows, 4 waves;
// wave w owns rows [w*16, w*16+16).  All LDS rows are produced and consumed
// by the same wave -> no barriers.  Coalesced float4 stores.
__global__ __launch_bounds__(256) void k_out(const ushort* __restrict__ S,
                                             const float* __restrict__ right,
                                             const ushort* __restrict__ Wfb,
                                             const float* __restrict__ bf,
                                             const int* __restrict__ deg,
                                             const float* __restrict__ sc_post,
                                             const ushort* __restrict__ W1b,
                                             const float* __restrict__ b1,
                                             const ushort* __restrict__ W2b,
                                             const float* __restrict__ b2,
                                             float* __restrict__ out, int n) {
    __shared__ ushort H[64][136];
    int t = threadIdx.x, wave = t >> 6, lane = t & 63;
    int m = lane & 15, quad = lane >> 4;
    size_t row0 = (size_t)blockIdx.x * 64;
    int rl = wave * 16 + m;
    size_t xrow = row0 + rl;
    size_t xrowc = (xrow < (size_t)n) ? xrow : (size_t)(n - 1);
    bool ok = (xrow < (size_t)n);
    float dd = ok ? (float)deg[xrow] : 0.f;
    float sp = sc_post[0];

    // S fragments (B operand) + right fragments (concat half of W1)
    short8 s4[4], ar[4];
    const ushort* sr = S + xrowc * EMB;
    const float* rr = right + xrowc * EMB;
#pragma unroll
    for (int ks = 0; ks < 4; ks++) {
        s4[ks] = *(const short8*)(sr + ks * 32 + quad * 8);
        ar[ks] = cvt8(rr + ks * 32 + quad * 8);
    }

    // ---- phase 1: conv = (S @ Wf^T + deg*bf) * sp -> H (own rows) ----
#pragma unroll
    for (int wt = 0; wt < 8; wt++) {
        floatx4 acc = {0.f, 0.f, 0.f, 0.f};
#pragma unroll
        for (int ks = 0; ks < 4; ks++) {
            short8 w = *(const short8*)(Wfb + (size_t)(wt * 16 + m) * EMB + ks * 32 + quad * 8);
            acc = MFMA(w, s4[ks], acc);
        }
        float4 bb = *(const float4*)(bf + wt * 16 + quad * 4);
        short4v o;
        o[0] = f2b((acc[0] + dd * bb.x) * sp);
        o[1] = f2b((acc[1] + dd * bb.y) * sp);
        o[2] = f2b((acc[2] + dd * bb.z) * sp);
        o[3] = f2b((acc[3] + dd * bb.w) * sp);
        *(short4v*)(&H[rl][wt * 16 + quad * 4]) = o;
    }

    // ---- phase 2: hidden = relu([conv ; right] @ W1^T + b1) -> H ----
    short8 c4[4];
#pragma unroll
    for (int ks = 0; ks < 4; ks++)
        c4[ks] = *(const short8*)(&H[rl][ks * 32 + quad * 8]);
#pragma unroll
    for (int wt = 0; wt < 8; wt++) {
        floatx4 acc = {0.f, 0.f, 0.f, 0.f};
        const ushort* wrow = W1b + (size_t)(wt * 16 + m) * 256;
#pragma unroll
        for (int ks = 0; ks < 4; ks++) {
            short8 w = *(const short8*)(wrow + ks * 32 + quad * 8);
            acc = MFMA(w, c4[ks], acc);
        }
#pragma unroll
        for (int ks = 0; ks < 4; ks++) {
            short8 w = *(const short8*)(wrow + 128 + ks * 32 + quad * 8);
            acc = MFMA(w, ar[ks], acc);
        }
        float4 bb = *(const float4*)(b1 + wt * 16 + quad * 4);
        short4v o;
        o[0] = f2b(fmaxf(acc[0] + bb.x, 0.f));
        o[1] = f2b(fmaxf(acc[1] + bb.y, 0.f));
        o[2] = f2b(fmaxf(acc[2] + bb.z, 0.f));
        o[3] = f2b(fmaxf(acc[3] + bb.w, 0.f));
        *(short4v*)(&H[rl][wt * 16 + quad * 4]) = o;
    }

    // ---- phase 3: out = hidden @ W2^T + b2 (coalesced float4 stores) ----
    short8 h4[4];
#pragma unroll
    for (int ks = 0; ks < 4; ks++)
        h4[ks] = *(const short8*)(&H[rl][ks * 32 + quad * 8]);
#pragma unroll
    for (int wt = 0; wt < 8; wt++) {
        floatx4 acc = {0.f, 0.f, 0.f, 0.f};
#pragma unroll
        for (int ks = 0; ks < 4; ks++) {
            short8 w = *(const short8*)(W2b + (size_t)(wt * 16 + m) * EMB + ks * 32 + quad * 8);
            acc = MFMA(w, h4[ks], acc);
        }
        if (ok) {
            float4 bb = *(const float4*)(b2 + wt * 16 + quad * 4);
            float4 o;
            o.x = acc[0] + bb.x;
            o.y = acc[1] + bb.y;
            o.z = acc[2] + bb.z;
            o.w = acc[3] + bb.w;
            *(float4*)(out + xrow * EMB + wt * 16 + quad * 4) = o;
        }
    }
}

// ---------------------------------------------------------------------------
extern "C" void kernel_launch(void* const* d_in, const int* in_sizes, int n_in,
                              void* d_out, int out_size, void* d_ws, size_t ws_size,
                              hipStream_t stream) {
    const float* left   = (const float*)d_in[0];
    const int*   eidx   = (const int*)  d_in[1];
    const float* efeat  = (const float*)d_in[2];
    const float* right  = (const float*)d_in[3];
    const float* W_left = (const float*)d_in[5];
    const float* b_left = (const float*)d_in[6];
    const float* W_edge = (const float*)d_in[7];
    const float* W_right= (const float*)d_in[8];
    const float* sc_fin = (const float*)d_in[9];
    const float* W_fin  = (const float*)d_in[10];
    const float* b_fin  = (const float*)d_in[11];
    const float* sc_post= (const float*)d_in[12];
    const float* W_out1 = (const float*)d_in[13];
    const float* b_out1 = (const float*)d_in[14];
    const float* W_out2 = (const float*)d_in[15];
    const float* b_out2 = (const float*)d_in[16];

    int n_left  = in_sizes[0] / EMB;        // 100000
    int n_edges = in_sizes[2];              // 600000
    int n_right = in_sizes[3] / EMB;        // 100000

    ushort* us = (ushort*)d_ws;
    ushort* Wl_b = us;                       // packed bf16 weights
    ushort* Wr_b = us + 16384;
    ushort* Wf_b = us + 32768;
    ushort* W1_b = us + 49152;
    ushort* W2_b = us + 81920;
    ushort* Pl   = us + 98304;               // n_left*128
    ushort* Pr   = Pl + (size_t)n_left * EMB;
    ushort* S    = Pr + (size_t)n_right * EMB;
    int* cnt    = (int*)(S + (size_t)n_right * EMB);
    int* offs   = cnt + n_right;
    int* cursor = offs + n_right;
    int* bsum   = cursor + n_right;
    int2* sle   = (int2*)(bsum + 64);

    hipMemsetAsync(cnt, 0, (size_t)n_right * sizeof(int), stream);

    int eb = (n_edges + 255) / 256;          // 2344
    int nblk = (n_left + 63) / 64;           // 1563

    // weights->bf16 + degree histogram (independent, one launch)
    k_cvthist<<<384 + eb, 256, 0, stream>>>(W_left, W_right, W_fin, W_out1,
                                            W_out2, us, eidx, cnt, n_edges);

    // exclusive scan of degrees
    int nsb = (n_right + SCAN_CHUNK - 1) / SCAN_CHUNK;   // 25
    k_scan1<<<nsb, 1024, 0, stream>>>(cnt, offs, bsum, n_right);
    k_scan2<<<nsb, 1024, 0, stream>>>(bsum, offs, cursor, n_right);

    // sorted edge list + both projections (independent, one launch)
    k_permproj<<<eb + 2 * nblk, 256, 0, stream>>>(eidx, efeat, cursor, sle,
                                                  n_edges, left, right,
                                                  Wl_b, Wr_b, b_left,
                                                  Pl, Pr, n_left, eb, nblk);

    // segmented reduction -> S (one wave per right node, 4-wide gather)
    k_reduce<<<(n_right + 3) / 4, 256, 0, stream>>>(Pl, Pr, sle, W_edge, offs,
                                                    sc_fin, S, n_right, n_edges);

    // conv GEMM + output MLP
    k_out<<<(n_right + 63) / 64, 256, 0, stream>>>(S, right, Wf_b, b_fin,
                                                   cnt, sc_post, W1_b, b_out1,
                                                   W2_b, b_out2,
                                                   (float*)d_out, n_right);
}

// Round 4
// 350.570 us; speedup vs baseline: 1.3296x; 1.2269x over previous
//
#include <hip/hip_runtime.h>

#define EMB 128

typedef __attribute__((ext_vector_type(8))) short short8;
typedef __attribute__((ext_vector_type(4))) short short4v;
typedef __attribute__((ext_vector_type(4))) float floatx4;

#define MFMA(a, b, c) __builtin_amdgcn_mfma_f32_16x16x32_bf16((a), (b), (c), 0, 0, 0)

__device__ __forceinline__ ushort f2b(float f) {
    unsigned u = __float_as_uint(f);
    return (ushort)((u + 0x7fff + ((u >> 16) & 1)) >> 16);   // RNE
}
__device__ __forceinline__ float b2f(ushort h) {
    return __uint_as_float(((unsigned)h) << 16);
}
__device__ __forceinline__ short8 cvt8(const float* p) {
    float4 f0 = *(const float4*)p;
    float4 f1 = *(const float4*)(p + 4);
    short8 v;
    v[0] = f2b(f0.x); v[1] = f2b(f0.y); v[2] = f2b(f0.z); v[3] = f2b(f0.w);
    v[4] = f2b(f1.x); v[5] = f2b(f1.y); v[6] = f2b(f1.z); v[7] = f2b(f1.w);
    return v;
}

// ---------------------------------------------------------------------------
// LDS weight staging with XOR swizzle.  Weight matrices are row-major with
// 256B (RSH=8) or 512B (RSH=9) rows.  Fragment reads are 16B at row-stride,
// which without swizzle is a 16-way bank conflict (all rows hit the same 4
// banks).  byte ^= ((row&7)<<4) spreads 8 rows across 8 distinct 16B slots
// (2-way residual conflict = free).  Staging writes apply the SAME xor so
// write/read agree; staged source is linear, lane-consecutive (coalesced).
template <int RSH>
__device__ __forceinline__ void stage32k(const ushort* __restrict__ g,
                                         ushort* __restrict__ lds, int t) {
#pragma unroll
    for (int i = 0; i < 8; i++) {
        int a = i * 4096 + t * 16;                       // linear byte offset
        short8 v = *(const short8*)(g + (a >> 1));
        int d = a ^ (((a >> RSH) & 7) << 4);
        *(short8*)((char*)lds + d) = v;
    }
}
__device__ __forceinline__ short8 ldsW8(const ushort* lds, int byte) {   // 256B rows
    return *(const short8*)((const char*)lds + (byte ^ (((byte >> 8) & 7) << 4)));
}
__device__ __forceinline__ short8 ldsW9(const ushort* lds, int byte) {   // 512B rows
    return *(const short8*)((const char*)lds + (byte ^ (((byte >> 9) & 7) << 4)));
}

// ---------------------------------------------------------------------------
// fused independent pre-work: blocks [0,384) convert the 5 weight matrices to
// bf16; blocks [384, 384+eb) histogram right indices.
__global__ __launch_bounds__(256) void k_cvthist(const float* __restrict__ w0,
                                                 const float* __restrict__ w1,
                                                 const float* __restrict__ w2,
                                                 const float* __restrict__ w3,
                                                 const float* __restrict__ w4,
                                                 ushort* __restrict__ dst,
                                                 const int* __restrict__ eidx,
                                                 int* __restrict__ cnt,
                                                 int n_edges) {
    int bid = blockIdx.x;
    if (bid < 384) {
        int i = bid * 256 + threadIdx.x;     // 0..98303
        const float* src; int off;
        if (i < 16384)      { src = w0; off = i; }
        else if (i < 32768) { src = w1; off = i - 16384; }
        else if (i < 49152) { src = w2; off = i - 32768; }
        else if (i < 81920) { src = w3; off = i - 49152; }
        else                { src = w4; off = i - 81920; }
        dst[i] = f2b(src[off]);
    } else {
        int e = (bid - 384) * 256 + threadIdx.x;
        if (e < n_edges) atomicAdd(&cnt[eidx[n_edges + e]], 1);
    }
}

#define SCAN_CHUNK 4096
__global__ __launch_bounds__(1024) void k_scan1(const int* __restrict__ cnt,
                                                int* __restrict__ offs,
                                                int* __restrict__ bsum, int n) {
    __shared__ int buf[1024];
    int t = threadIdx.x;
    int i0 = blockIdx.x * SCAN_CHUNK + t * 4;
    int v[4];
#pragma unroll
    for (int u = 0; u < 4; u++) { int i = i0 + u; v[u] = (i < n) ? cnt[i] : 0; }
    int s = v[0] + v[1] + v[2] + v[3];
    buf[t] = s;
    __syncthreads();
    for (int d = 1; d < 1024; d <<= 1) {
        int x = (t >= d) ? buf[t - d] : 0;
        __syncthreads();
        buf[t] += x;
        __syncthreads();
    }
    int excl = buf[t] - s;
#pragma unroll
    for (int u = 0; u < 4; u++) { int i = i0 + u; if (i < n) offs[i] = excl; excl += v[u]; }
    if (t == 1023) bsum[blockIdx.x] = buf[1023];
}

__global__ __launch_bounds__(1024) void k_scan2(const int* __restrict__ bsum,
                                                int* __restrict__ offs,
                                                int* __restrict__ cursor, int n) {
    int bid = blockIdx.x;
    int base = 0;
    for (int j = 0; j < bid; j++) base += bsum[j];
    int i0 = bid * SCAN_CHUNK + threadIdx.x * 4;
#pragma unroll
    for (int u = 0; u < 4; u++) {
        int i = i0 + u;
        if (i < n) { int o = offs[i] + base; offs[i] = o; cursor[i] = o; }
    }
}

// ---------------------------------------------------------------------------
// fused: blocks [0,eb) -> perm (sorted (li,ef) list); [eb, eb+nblk) -> left
// projection; [eb+nblk, eb+2*nblk) -> right projection.
// Swapped MFMA operands (wave owns 16 rows x all 128 cols, X read once,
// 8B coalesced stores).  NEW: weight matrix staged to LDS once per block
// (was: 32KB re-read from L2 by EVERY wave -> 400MB L2 + latency on the
// MFMA critical path).
__global__ __launch_bounds__(256) void k_permproj(const int* __restrict__ eidx,
                                                  const float* __restrict__ ef,
                                                  int* __restrict__ cursor,
                                                  int2* __restrict__ sle,
                                                  int n_edges,
                                                  const float* __restrict__ XL,
                                                  const float* __restrict__ XR,
                                                  const ushort* __restrict__ WLb,
                                                  const ushort* __restrict__ WRb,
                                                  const float* __restrict__ bias,
                                                  ushort* __restrict__ YL,
                                                  ushort* __restrict__ YR,
                                                  int n, int eb, int nblk) {
    __shared__ ushort Wlds[16384];
    int bid = blockIdx.x;
    if (bid < eb) {
        int e = bid * 256 + threadIdx.x;
        if (e < n_edges) {
            int r = eidx[n_edges + e];
            int p = atomicAdd(&cursor[r], 1);
            int2 v; v.x = eidx[e]; v.y = __float_as_int(ef[e]);
            sle[p] = v;
        }
        return;
    }
    bid -= eb;
    const float* X; const ushort* Wb; ushort* Y; int has_bias;
    if (bid < nblk) { X = XL; Wb = WLb; Y = YL; has_bias = 1; }
    else            { X = XR; Wb = WRb; Y = YR; has_bias = 0; bid -= nblk; }

    int t = threadIdx.x, wave = t >> 6, lane = t & 63;
    int m = lane & 15, quad = lane >> 4;
    size_t row0 = (size_t)bid * 64;
    size_t row = row0 + wave * 16 + m;
    size_t rowc = (row < (size_t)n) ? row : (size_t)(n - 1);

    stage32k<8>(Wb, Wlds, t);

    short8 xf[4];
    const float* xr = X + rowc * EMB;
#pragma unroll
    for (int ks = 0; ks < 4; ks++)
        xf[ks] = cvt8(xr + ks * 32 + quad * 8);

    __syncthreads();   // weights staged

    bool ok = (row < (size_t)n);
#pragma unroll
    for (int wt = 0; wt < 8; wt++) {
        floatx4 acc = {0.f, 0.f, 0.f, 0.f};
#pragma unroll
        for (int ks = 0; ks < 4; ks++) {
            short8 w = ldsW8(Wlds, ((wt * 16 + m) << 8) + (ks << 6) + (quad << 4));
            acc = MFMA(w, xf[ks], acc);
        }
        float b0 = 0.f, b1_ = 0.f, b2_ = 0.f, b3 = 0.f;
        if (has_bias) {
            float4 bb = *(const float4*)(bias + wt * 16 + quad * 4);
            b0 = bb.x; b1_ = bb.y; b2_ = bb.z; b3 = bb.w;
        }
        if (ok) {
            short4v o;
            o[0] = f2b(acc[0] + b0);
            o[1] = f2b(acc[1] + b1_);
            o[2] = f2b(acc[2] + b2_);
            o[3] = f2b(acc[3] + b3);
            *(short4v*)(Y + row * EMB + wt * 16 + quad * 4) = o;
        }
    }
}

// ---------------------------------------------------------------------------
// segmented reduction: unchanged from round 3 (one wave per right node,
// 4 edge-groups x 16 lanes x 8 cols, 8 gathers in flight).
__global__ __launch_bounds__(256) void k_reduce(const ushort* __restrict__ Pl,
                                                const ushort* __restrict__ Pr,
                                                const int2* __restrict__ sle,
                                                const float* __restrict__ We,
                                                const int* __restrict__ offs,
                                                const float* __restrict__ scale_final,
                                                ushort* __restrict__ S,
                                                int n_right, int n_edges) {
    int r = blockIdx.x * 4 + (threadIdx.x >> 6);
    if (r >= n_right) return;
    int lane = threadIdx.x & 63;
    int g = lane >> 4;          // edge group 0..3
    int m = lane & 15;          // column group: cols [m*8, m*8+8)
    float scale = scale_final[0];

    float4 w0 = *(const float4*)(We + m * 8);
    float4 w1 = *(const float4*)(We + m * 8 + 4);
    short8 prv = *(const short8*)(Pr + (size_t)r * EMB + m * 8);
    float we[8], pr[8];
    we[0] = w0.x; we[1] = w0.y; we[2] = w0.z; we[3] = w0.w;
    we[4] = w1.x; we[5] = w1.y; we[6] = w1.z; we[7] = w1.w;
#pragma unroll
    for (int j = 0; j < 8; j++) pr[j] = b2f((ushort)prv[j]);

    float acc[8] = {0.f, 0.f, 0.f, 0.f, 0.f, 0.f, 0.f, 0.f};
    int s0 = offs[r];
    int s1 = (r + 1 < n_right) ? offs[r + 1] : n_edges;
    int e = s0 + g;
    for (; e + 4 < s1; e += 8) {       // two edges per group in flight
        int2 ea = sle[e];
        int2 eb = sle[e + 4];
        short8 pa = *(const short8*)(Pl + (size_t)ea.x * EMB + m * 8);
        short8 pb = *(const short8*)(Pl + (size_t)eb.x * EMB + m * 8);
        float fa = __int_as_float(ea.y), fb = __int_as_float(eb.y);
#pragma unroll
        for (int j = 0; j < 8; j++) {
            acc[j] += fmaxf((b2f((ushort)pa[j]) + pr[j] + fa * we[j]) * scale, 0.f);
            acc[j] += fmaxf((b2f((ushort)pb[j]) + pr[j] + fb * we[j]) * scale, 0.f);
        }
    }
    if (e < s1) {                      // at most one leftover per group
        int2 ea = sle[e];
        short8 pa = *(const short8*)(Pl + (size_t)ea.x * EMB + m * 8);
        float fa = __int_as_float(ea.y);
#pragma unroll
        for (int j = 0; j < 8; j++)
            acc[j] += fmaxf((b2f((ushort)pa[j]) + pr[j] + fa * we[j]) * scale, 0.f);
    }
#pragma unroll
    for (int j = 0; j < 8; j++) {
        acc[j] += __shfl_xor(acc[j], 16);
        acc[j] += __shfl_xor(acc[j], 32);
    }
    if (g == 0) {
        short8 o;
#pragma unroll
        for (int j = 0; j < 8; j++) o[j] = f2b(acc[j]);
        *(short8*)(S + (size_t)r * EMB + m * 8) = o;
    }
}

// ---------------------------------------------------------------------------
// conv GEMM + output MLP with LDS-staged weights (phase-synchronized).
// Block = 64 rows, 4 waves, wave owns 16 rows.  One 32KB LDS weight buffer
// staged 4x: Wf -> W1[rows 0..63] -> W1[rows 64..127] -> W2 (phase 2 splits
// by output-column group wt, which is clean since each wt accumulates
// independently).  All weight reads are swizzled ds_read_b128.  Global
// traffic per wave is just its own S/right rows + out stores, issued in
// bulk; weight L2 chatter (was 128KB per WAVE) is now 128KB per BLOCK.
__global__ __launch_bounds__(256) void k_out(const ushort* __restrict__ S,
                                             const float* __restrict__ right,
                                             const ushort* __restrict__ Wfb,
                                             const float* __restrict__ bf,
                                             const int* __restrict__ deg,
                                             const float* __restrict__ sc_post,
                                             const ushort* __restrict__ W1b,
                                             const float* __restrict__ b1,
                                             const ushort* __restrict__ W2b,
                                             const float* __restrict__ b2,
                                             float* __restrict__ out, int n) {
    __shared__ ushort Wlds[16384];       // 32KB staging buffer
    __shared__ ushort H[64][136];
    __shared__ float degs[64];
    int t = threadIdx.x, wave = t >> 6, lane = t & 63;
    int m = lane & 15, quad = lane >> 4;
    size_t row0 = (size_t)blockIdx.x * 64;
    int rl = wave * 16 + m;
    size_t xrow = row0 + rl;
    size_t xrowc = (xrow < (size_t)n) ? xrow : (size_t)(n - 1);
    bool ok = (xrow < (size_t)n);
    float sp = sc_post[0];

    // prologue: issue all per-wave global loads early
    short8 s4[4], ar[4];
    const ushort* sr = S + xrowc * EMB;
    const float* rr = right + xrowc * EMB;
#pragma unroll
    for (int ks = 0; ks < 4; ks++)
        s4[ks] = *(const short8*)(sr + ks * 32 + quad * 8);
    stage32k<8>(Wfb, Wlds, t);
#pragma unroll
    for (int ks = 0; ks < 4; ks++)
        ar[ks] = cvt8(rr + ks * 32 + quad * 8);
    if (t < 64) {
        size_t rr2 = row0 + t;
        degs[t] = (rr2 < (size_t)n) ? (float)deg[rr2] : 0.f;
    }
    __syncthreads();                      // Wf + degs ready
    float dd = degs[rl];

    // ---- phase 1: conv = (S @ Wf^T + deg*bf) * sp -> H ----
#pragma unroll
    for (int wt = 0; wt < 8; wt++) {
        floatx4 acc = {0.f, 0.f, 0.f, 0.f};
#pragma unroll
        for (int ks = 0; ks < 4; ks++) {
            short8 w = ldsW8(Wlds, ((wt * 16 + m) << 8) + (ks << 6) + (quad << 4));
            acc = MFMA(w, s4[ks], acc);
        }
        float4 bb = *(const float4*)(bf + wt * 16 + quad * 4);
        short4v o;
        o[0] = f2b((acc[0] + dd * bb.x) * sp);
        o[1] = f2b((acc[1] + dd * bb.y) * sp);
        o[2] = f2b((acc[2] + dd * bb.z) * sp);
        o[3] = f2b((acc[3] + dd * bb.w) * sp);
        *(short4v*)(&H[rl][wt * 16 + quad * 4]) = o;
    }
    // conv B-frags (wave-local H rows; lgkmcnt orders within the wave)
    short8 c4[4];
#pragma unroll
    for (int ks = 0; ks < 4; ks++)
        c4[ks] = *(const short8*)(&H[rl][ks * 32 + quad * 8]);
    __syncthreads();                      // all waves done reading Wf
    stage32k<9>(W1b, Wlds, t);            // W1 rows 0..63 (out cols 0..63)
    __syncthreads();

    // ---- phase 2a: hidden cols 0..63 ----
#pragma unroll
    for (int wt = 0; wt < 4; wt++) {
        floatx4 acc = {0.f, 0.f, 0.f, 0.f};
        int rb = wt * 16 + m;             // buffer-local W1 row
#pragma unroll
        for (int ks = 0; ks < 4; ks++) {
            short8 w = ldsW9(Wlds, (rb << 9) + (ks << 6) + (quad << 4));
            acc = MFMA(w, c4[ks], acc);
        }
#pragma unroll
        for (int ks = 0; ks < 4; ks++) {
            short8 w = ldsW9(Wlds, (rb << 9) + 256 + (ks << 6) + (quad << 4));
            acc = MFMA(w, ar[ks], acc);
        }
        float4 bb = *(const float4*)(b1 + wt * 16 + quad * 4);
        short4v o;
        o[0] = f2b(fmaxf(acc[0] + bb.x, 0.f));
        o[1] = f2b(fmaxf(acc[1] + bb.y, 0.f));
        o[2] = f2b(fmaxf(acc[2] + bb.z, 0.f));
        o[3] = f2b(fmaxf(acc[3] + bb.w, 0.f));
        *(short4v*)(&H[rl][wt * 16 + quad * 4]) = o;
    }
    __syncthreads();                      // done reading W1a
    stage32k<9>(W1b + 16384, Wlds, t);    // W1 rows 64..127
    __syncthreads();

    // ---- phase 2b: hidden cols 64..127 ----
#pragma unroll
    for (int wt = 4; wt < 8; wt++) {
        floatx4 acc = {0.f, 0.f, 0.f, 0.f};
        int rb = (wt - 4) * 16 + m;
#pragma unroll
        for (int ks = 0; ks < 4; ks++) {
            short8 w = ldsW9(Wlds, (rb << 9) + (ks << 6) + (quad << 4));
            acc = MFMA(w, c4[ks], acc);
        }
#pragma unroll
        for (int ks = 0; ks < 4; ks++) {
            short8 w = ldsW9(Wlds, (rb << 9) + 256 + (ks << 6) + (quad << 4));
            acc = MFMA(w, ar[ks], acc);
        }
        float4 bb = *(const float4*)(b1 + wt * 16 + quad * 4);
        short4v o;
        o[0] = f2b(fmaxf(acc[0] + bb.x, 0.f));
        o[1] = f2b(fmaxf(acc[1] + bb.y, 0.f));
        o[2] = f2b(fmaxf(acc[2] + bb.z, 0.f));
        o[3] = f2b(fmaxf(acc[3] + bb.w, 0.f));
        *(short4v*)(&H[rl][wt * 16 + quad * 4]) = o;
    }
    short8 h4[4];
#pragma unroll
    for (int ks = 0; ks < 4; ks++)
        h4[ks] = *(const short8*)(&H[rl][ks * 32 + quad * 8]);
    __syncthreads();                      // done reading W1b
    stage32k<8>(W2b, Wlds, t);
    __syncthreads();

    // ---- phase 3: out = hidden @ W2^T + b2 (coalesced float4 stores) ----
#pragma unroll
    for (int wt = 0; wt < 8; wt++) {
        floatx4 acc = {0.f, 0.f, 0.f, 0.f};
#pragma unroll
        for (int ks = 0; ks < 4; ks++) {
            short8 w = ldsW8(Wlds, ((wt * 16 + m) << 8) + (ks << 6) + (quad << 4));
            acc = MFMA(w, h4[ks], acc);
        }
        if (ok) {
            float4 bb = *(const float4*)(b2 + wt * 16 + quad * 4);
            float4 o;
            o.x = acc[0] + bb.x;
            o.y = acc[1] + bb.y;
            o.z = acc[2] + bb.z;
            o.w = acc[3] + bb.w;
            *(float4*)(out + xrow * EMB + wt * 16 + quad * 4) = o;
        }
    }
}

// ---------------------------------------------------------------------------
extern "C" void kernel_launch(void* const* d_in, const int* in_sizes, int n_in,
                              void* d_out, int out_size, void* d_ws, size_t ws_size,
                              hipStream_t stream) {
    const float* left   = (const float*)d_in[0];
    const int*   eidx   = (const int*)  d_in[1];
    const float* efeat  = (const float*)d_in[2];
    const float* right  = (const float*)d_in[3];
    const float* W_left = (const float*)d_in[5];
    const float* b_left = (const float*)d_in[6];
    const float* W_edge = (const float*)d_in[7];
    const float* W_right= (const float*)d_in[8];
    const float* sc_fin = (const float*)d_in[9];
    const float* W_fin  = (const float*)d_in[10];
    const float* b_fin  = (const float*)d_in[11];
    const float* sc_post= (const float*)d_in[12];
    const float* W_out1 = (const float*)d_in[13];
    const float* b_out1 = (const float*)d_in[14];
    const float* W_out2 = (const float*)d_in[15];
    const float* b_out2 = (const float*)d_in[16];

    int n_left  = in_sizes[0] / EMB;        // 100000
    int n_edges = in_sizes[2];              // 600000
    int n_right = in_sizes[3] / EMB;        // 100000

    ushort* us = (ushort*)d_ws;
    ushort* Wl_b = us;                       // packed bf16 weights
    ushort* Wr_b = us + 16384;
    ushort* Wf_b = us + 32768;
    ushort* W1_b = us + 49152;
    ushort* W2_b = us + 81920;
    ushort* Pl   = us + 98304;               // n_left*128
    ushort* Pr   = Pl + (size_t)n_left * EMB;
    ushort* S    = Pr + (size_t)n_right * EMB;
    int* cnt    = (int*)(S + (size_t)n_right * EMB);
    int* offs   = cnt + n_right;
    int* cursor = offs + n_right;
    int* bsum   = cursor + n_right;
    int2* sle   = (int2*)(bsum + 64);

    hipMemsetAsync(cnt, 0, (size_t)n_right * sizeof(int), stream);

    int eb = (n_edges + 255) / 256;          // 2344
    int nblk = (n_left + 63) / 64;           // 1563

    // weights->bf16 + degree histogram (independent, one launch)
    k_cvthist<<<384 + eb, 256, 0, stream>>>(W_left, W_right, W_fin, W_out1,
                                            W_out2, us, eidx, cnt, n_edges);

    // exclusive scan of degrees
    int nsb = (n_right + SCAN_CHUNK - 1) / SCAN_CHUNK;   // 25
    k_scan1<<<nsb, 1024, 0, stream>>>(cnt, offs, bsum, n_right);
    k_scan2<<<nsb, 1024, 0, stream>>>(bsum, offs, cursor, n_right);

    // sorted edge list + both projections (independent, one launch)
    k_permproj<<<eb + 2 * nblk, 256, 0, stream>>>(eidx, efeat, cursor, sle,
                                                  n_edges, left, right,
                                                  Wl_b, Wr_b, b_left,
                                                  Pl, Pr, n_left, eb, nblk);

    // segmented reduction -> S (one wave per right node, 4-wide gather)
    k_reduce<<<(n_right + 3) / 4, 256, 0, stream>>>(Pl, Pr, sle, W_edge, offs,
                                                    sc_fin, S, n_right, n_edges);

    // conv GEMM + output MLP (LDS-staged weights)
    k_out<<<(n_right + 63) / 64, 256, 0, stream>>>(S, right, Wf_b, b_fin,
                                                   cnt, sc_post, W1_b, b_out1,
                                                   W2_b, b_out2,
                                                   (float*)d_out, n_right);
}

// Round 5
// 346.254 us; speedup vs baseline: 1.3461x; 1.0125x over previous
//
#include <hip/hip_runtime.h>

#define EMB 128

typedef __attribute__((ext_vector_type(8))) short short8;
typedef __attribute__((ext_vector_type(4))) short short4v;
typedef __attribute__((ext_vector_type(4))) float floatx4;

#define MFMA(a, b, c) __builtin_amdgcn_mfma_f32_16x16x32_bf16((a), (b), (c), 0, 0, 0)

__device__ __forceinline__ ushort f2b(float f) {
    unsigned u = __float_as_uint(f);
    return (ushort)((u + 0x7fff + ((u >> 16) & 1)) >> 16);   // RNE
}
__device__ __forceinline__ float b2f(ushort h) {
    return __uint_as_float(((unsigned)h) << 16);
}
__device__ __forceinline__ short8 cvt8(const float* p) {
    float4 f0 = *(const float4*)p;
    float4 f1 = *(const float4*)(p + 4);
    short8 v;
    v[0] = f2b(f0.x); v[1] = f2b(f0.y); v[2] = f2b(f0.z); v[3] = f2b(f0.w);
    v[4] = f2b(f1.x); v[5] = f2b(f1.y); v[6] = f2b(f1.z); v[7] = f2b(f1.w);
    return v;
}

// ---------------------------------------------------------------------------
// LDS weight staging with XOR swizzle (proven round 4).  byte ^= ((row&7)<<4)
// spreads row-strided 16B fragment reads across 8 bank slots (2-way residual
// conflict = free).  RSH = log2(row bytes).
template <int RSH>
__device__ __forceinline__ void stage32k(const ushort* __restrict__ g,
                                         ushort* __restrict__ lds, int t) {
#pragma unroll
    for (int i = 0; i < 8; i++) {
        int a = i * 4096 + t * 16;                       // linear byte offset
        short8 v = *(const short8*)(g + (a >> 1));
        int d = a ^ (((a >> RSH) & 7) << 4);
        *(short8*)((char*)lds + d) = v;
    }
}
__device__ __forceinline__ short8 ldsW8(const ushort* lds, int byte) {   // 256B rows
    return *(const short8*)((const char*)lds + (byte ^ (((byte >> 8) & 7) << 4)));
}
__device__ __forceinline__ short8 ldsW9(const ushort* lds, int byte) {   // 512B rows
    return *(const short8*)((const char*)lds + (byte ^ (((byte >> 9) & 7) << 4)));
}

// ---------------------------------------------------------------------------
// fused independent pre-work: blocks [0,384) convert the 5 weight matrices to
// bf16; blocks [384, 384+eb) histogram right indices.
__global__ __launch_bounds__(256) void k_cvthist(const float* __restrict__ w0,
                                                 const float* __restrict__ w1,
                                                 const float* __restrict__ w2,
                                                 const float* __restrict__ w3,
                                                 const float* __restrict__ w4,
                                                 ushort* __restrict__ dst,
                                                 const int* __restrict__ eidx,
                                                 int* __restrict__ cnt,
                                                 int n_edges) {
    int bid = blockIdx.x;
    if (bid < 384) {
        int i = bid * 256 + threadIdx.x;     // 0..98303
        const float* src; int off;
        if (i < 16384)      { src = w0; off = i; }
        else if (i < 32768) { src = w1; off = i - 16384; }
        else if (i < 49152) { src = w2; off = i - 32768; }
        else if (i < 81920) { src = w3; off = i - 49152; }
        else                { src = w4; off = i - 81920; }
        dst[i] = f2b(src[off]);
    } else {
        int e = (bid - 384) * 256 + threadIdx.x;
        if (e < n_edges) atomicAdd(&cnt[eidx[n_edges + e]], 1);
    }
}

#define SCAN_CHUNK 4096
__global__ __launch_bounds__(1024) void k_scan1(const int* __restrict__ cnt,
                                                int* __restrict__ offs,
                                                int* __restrict__ bsum, int n) {
    __shared__ int buf[1024];
    int t = threadIdx.x;
    int i0 = blockIdx.x * SCAN_CHUNK + t * 4;
    int v[4];
#pragma unroll
    for (int u = 0; u < 4; u++) { int i = i0 + u; v[u] = (i < n) ? cnt[i] : 0; }
    int s = v[0] + v[1] + v[2] + v[3];
    buf[t] = s;
    __syncthreads();
    for (int d = 1; d < 1024; d <<= 1) {
        int x = (t >= d) ? buf[t - d] : 0;
        __syncthreads();
        buf[t] += x;
        __syncthreads();
    }
    int excl = buf[t] - s;
#pragma unroll
    for (int u = 0; u < 4; u++) { int i = i0 + u; if (i < n) offs[i] = excl; excl += v[u]; }
    if (t == 1023) bsum[blockIdx.x] = buf[1023];
}

__global__ __launch_bounds__(1024) void k_scan2(const int* __restrict__ bsum,
                                                int* __restrict__ offs,
                                                int* __restrict__ cursor, int n) {
    int bid = blockIdx.x;
    int base = 0;
    for (int j = 0; j < bid; j++) base += bsum[j];
    int i0 = bid * SCAN_CHUNK + threadIdx.x * 4;
#pragma unroll
    for (int u = 0; u < 4; u++) {
        int i = i0 + u;
        if (i < n) { int o = offs[i] + base; offs[i] = o; cursor[i] = o; }
    }
}

// ---------------------------------------------------------------------------
// fused: blocks [0,eb) -> perm (sorted (li,ef) list); then 2*PROJ_PB
// PERSISTENT projection blocks (left then right).  Each proj block stages
// its 32KB weight matrix to LDS ONCE, then grid-strides over 128-row tiles
// (4 waves x 32 rows/wave, 2 row-groups).  No barrier inside the tile loop
// (weights read-only after one sync) -> consecutive tiles pipeline: next
// tile's 16x16B X loads issue under the current tile's 64 MFMAs.
#define PROJ_PB 512
__global__ __launch_bounds__(256) void k_permproj(const int* __restrict__ eidx,
                                                  const float* __restrict__ ef,
                                                  int* __restrict__ cursor,
                                                  int2* __restrict__ sle,
                                                  int n_edges,
                                                  const float* __restrict__ XL,
                                                  const float* __restrict__ XR,
                                                  const ushort* __restrict__ WLb,
                                                  const ushort* __restrict__ WRb,
                                                  const float* __restrict__ bias,
                                                  ushort* __restrict__ YL,
                                                  ushort* __restrict__ YR,
                                                  int n, int eb) {
    __shared__ ushort Wlds[16384];
    int bid = blockIdx.x;
    if (bid < eb) {
        int e = bid * 256 + threadIdx.x;
        if (e < n_edges) {
            int r = eidx[n_edges + e];
            int p = atomicAdd(&cursor[r], 1);
            int2 v; v.x = eidx[e]; v.y = __float_as_int(ef[e]);
            sle[p] = v;
        }
        return;
    }
    bid -= eb;
    const float* X; const ushort* Wb; ushort* Y; int has_bias;
    if (bid < PROJ_PB) { X = XL; Wb = WLb; Y = YL; has_bias = 1; }
    else               { X = XR; Wb = WRb; Y = YR; has_bias = 0; bid -= PROJ_PB; }

    int t = threadIdx.x, wave = t >> 6, lane = t & 63;
    int m = lane & 15, quad = lane >> 4;

    stage32k<8>(Wb, Wlds, t);
    __syncthreads();                      // weights staged once

    int ntiles = (n + 127) >> 7;
    for (int tile = bid; tile < ntiles; tile += PROJ_PB) {
        size_t base = (size_t)tile * 128 + wave * 32;
        size_t ra = base + m;
        size_t rb = base + 16 + m;
        bool oka = ra < (size_t)n, okb = rb < (size_t)n;
        size_t rac = oka ? ra : (size_t)(n - 1);
        size_t rbc = okb ? rb : (size_t)(n - 1);
        const float* pa = X + rac * EMB;
        const float* pb = X + rbc * EMB;
        short8 xa[4], xb[4];
#pragma unroll
        for (int ks = 0; ks < 4; ks++) {
            xa[ks] = cvt8(pa + ks * 32 + quad * 8);
            xb[ks] = cvt8(pb + ks * 32 + quad * 8);
        }
#pragma unroll
        for (int wt = 0; wt < 8; wt++) {
            floatx4 a0 = {0.f, 0.f, 0.f, 0.f}, a1 = {0.f, 0.f, 0.f, 0.f};
#pragma unroll
            for (int ks = 0; ks < 4; ks++) {
                short8 w = ldsW8(Wlds, ((wt * 16 + m) << 8) + (ks << 6) + (quad << 4));
                a0 = MFMA(w, xa[ks], a0);
                a1 = MFMA(w, xb[ks], a1);
            }
            float b0 = 0.f, b1_ = 0.f, b2_ = 0.f, b3 = 0.f;
            if (has_bias) {
                float4 bb = *(const float4*)(bias + wt * 16 + quad * 4);
                b0 = bb.x; b1_ = bb.y; b2_ = bb.z; b3 = bb.w;
            }
            if (oka) {
                short4v o;
                o[0] = f2b(a0[0] + b0);
                o[1] = f2b(a0[1] + b1_);
                o[2] = f2b(a0[2] + b2_);
                o[3] = f2b(a0[3] + b3);
                *(short4v*)(Y + ra * EMB + wt * 16 + quad * 4) = o;
            }
            if (okb) {
                short4v o;
                o[0] = f2b(a1[0] + b0);
                o[1] = f2b(a1[1] + b1_);
                o[2] = f2b(a1[2] + b2_);
                o[3] = f2b(a1[3] + b3);
                *(short4v*)(Y + rb * EMB + wt * 16 + quad * 4) = o;
            }
        }
    }
}

// ---------------------------------------------------------------------------
// segmented reduction: unchanged (one wave per right node, 4 edge-groups x
// 16 lanes x 8 cols, 8 gathers in flight).
__global__ __launch_bounds__(256) void k_reduce(const ushort* __restrict__ Pl,
                                                const ushort* __restrict__ Pr,
                                                const int2* __restrict__ sle,
                                                const float* __restrict__ We,
                                                const int* __restrict__ offs,
                                                const float* __restrict__ scale_final,
                                                ushort* __restrict__ S,
                                                int n_right, int n_edges) {
    int r = blockIdx.x * 4 + (threadIdx.x >> 6);
    if (r >= n_right) return;
    int lane = threadIdx.x & 63;
    int g = lane >> 4;          // edge group 0..3
    int m = lane & 15;          // column group: cols [m*8, m*8+8)
    float scale = scale_final[0];

    float4 w0 = *(const float4*)(We + m * 8);
    float4 w1 = *(const float4*)(We + m * 8 + 4);
    short8 prv = *(const short8*)(Pr + (size_t)r * EMB + m * 8);
    float we[8], pr[8];
    we[0] = w0.x; we[1] = w0.y; we[2] = w0.z; we[3] = w0.w;
    we[4] = w1.x; we[5] = w1.y; we[6] = w1.z; we[7] = w1.w;
#pragma unroll
    for (int j = 0; j < 8; j++) pr[j] = b2f((ushort)prv[j]);

    float acc[8] = {0.f, 0.f, 0.f, 0.f, 0.f, 0.f, 0.f, 0.f};
    int s0 = offs[r];
    int s1 = (r + 1 < n_right) ? offs[r + 1] : n_edges;
    int e = s0 + g;
    for (; e + 4 < s1; e += 8) {       // two edges per group in flight
        int2 ea = sle[e];
        int2 eb = sle[e + 4];
        short8 pa = *(const short8*)(Pl + (size_t)ea.x * EMB + m * 8);
        short8 pb = *(const short8*)(Pl + (size_t)eb.x * EMB + m * 8);
        float fa = __int_as_float(ea.y), fb = __int_as_float(eb.y);
#pragma unroll
        for (int j = 0; j < 8; j++) {
            acc[j] += fmaxf((b2f((ushort)pa[j]) + pr[j] + fa * we[j]) * scale, 0.f);
            acc[j] += fmaxf((b2f((ushort)pb[j]) + pr[j] + fb * we[j]) * scale, 0.f);
        }
    }
    if (e < s1) {                      // at most one leftover per group
        int2 ea = sle[e];
        short8 pa = *(const short8*)(Pl + (size_t)ea.x * EMB + m * 8);
        float fa = __int_as_float(ea.y);
#pragma unroll
        for (int j = 0; j < 8; j++)
            acc[j] += fmaxf((b2f((ushort)pa[j]) + pr[j] + fa * we[j]) * scale, 0.f);
    }
#pragma unroll
    for (int j = 0; j < 8; j++) {
        acc[j] += __shfl_xor(acc[j], 16);
        acc[j] += __shfl_xor(acc[j], 32);
    }
    if (g == 0) {
        short8 o;
#pragma unroll
        for (int j = 0; j < 8; j++) o[j] = f2b(acc[j]);
        *(short8*)(S + (size_t)r * EMB + m * 8) = o;
    }
}

// ---------------------------------------------------------------------------
// conv GEMM + output MLP with LDS-staged weights (unchanged from round 4).
__global__ __launch_bounds__(256) void k_out(const ushort* __restrict__ S,
                                             const float* __restrict__ right,
                                             const ushort* __restrict__ Wfb,
                                             const float* __restrict__ bf,
                                             const int* __restrict__ deg,
                                             const float* __restrict__ sc_post,
                                             const ushort* __restrict__ W1b,
                                             const float* __restrict__ b1,
                                             const ushort* __restrict__ W2b,
                                             const float* __restrict__ b2,
                                             float* __restrict__ out, int n) {
    __shared__ ushort Wlds[16384];       // 32KB staging buffer
    __shared__ ushort H[64][136];
    __shared__ float degs[64];
    int t = threadIdx.x, wave = t >> 6, lane = t & 63;
    int m = lane & 15, quad = lane >> 4;
    size_t row0 = (size_t)blockIdx.x * 64;
    int rl = wave * 16 + m;
    size_t xrow = row0 + rl;
    size_t xrowc = (xrow < (size_t)n) ? xrow : (size_t)(n - 1);
    bool ok = (xrow < (size_t)n);
    float sp = sc_post[0];

    // prologue: issue all per-wave global loads early
    short8 s4[4], ar[4];
    const ushort* sr = S + xrowc * EMB;
    const float* rr = right + xrowc * EMB;
#pragma unroll
    for (int ks = 0; ks < 4; ks++)
        s4[ks] = *(const short8*)(sr + ks * 32 + quad * 8);
    stage32k<8>(Wfb, Wlds, t);
#pragma unroll
    for (int ks = 0; ks < 4; ks++)
        ar[ks] = cvt8(rr + ks * 32 + quad * 8);
    if (t < 64) {
        size_t rr2 = row0 + t;
        degs[t] = (rr2 < (size_t)n) ? (float)deg[rr2] : 0.f;
    }
    __syncthreads();                      // Wf + degs ready
    float dd = degs[rl];

    // ---- phase 1: conv = (S @ Wf^T + deg*bf) * sp -> H ----
#pragma unroll
    for (int wt = 0; wt < 8; wt++) {
        floatx4 acc = {0.f, 0.f, 0.f, 0.f};
#pragma unroll
        for (int ks = 0; ks < 4; ks++) {
            short8 w = ldsW8(Wlds, ((wt * 16 + m) << 8) + (ks << 6) + (quad << 4));
            acc = MFMA(w, s4[ks], acc);
        }
        float4 bb = *(const float4*)(bf + wt * 16 + quad * 4);
        short4v o;
        o[0] = f2b((acc[0] + dd * bb.x) * sp);
        o[1] = f2b((acc[1] + dd * bb.y) * sp);
        o[2] = f2b((acc[2] + dd * bb.z) * sp);
        o[3] = f2b((acc[3] + dd * bb.w) * sp);
        *(short4v*)(&H[rl][wt * 16 + quad * 4]) = o;
    }
    // conv B-frags (wave-local H rows; lgkmcnt orders within the wave)
    short8 c4[4];
#pragma unroll
    for (int ks = 0; ks < 4; ks++)
        c4[ks] = *(const short8*)(&H[rl][ks * 32 + quad * 8]);
    __syncthreads();                      // all waves done reading Wf
    stage32k<9>(W1b, Wlds, t);            // W1 rows 0..63 (out cols 0..63)
    __syncthreads();

    // ---- phase 2a: hidden cols 0..63 ----
#pragma unroll
    for (int wt = 0; wt < 4; wt++) {
        floatx4 acc = {0.f, 0.f, 0.f, 0.f};
        int rb = wt * 16 + m;             // buffer-local W1 row
#pragma unroll
        for (int ks = 0; ks < 4; ks++) {
            short8 w = ldsW9(Wlds, (rb << 9) + (ks << 6) + (quad << 4));
            acc = MFMA(w, c4[ks], acc);
        }
#pragma unroll
        for (int ks = 0; ks < 4; ks++) {
            short8 w = ldsW9(Wlds, (rb << 9) + 256 + (ks << 6) + (quad << 4));
            acc = MFMA(w, ar[ks], acc);
        }
        float4 bb = *(const float4*)(b1 + wt * 16 + quad * 4);
        short4v o;
        o[0] = f2b(fmaxf(acc[0] + bb.x, 0.f));
        o[1] = f2b(fmaxf(acc[1] + bb.y, 0.f));
        o[2] = f2b(fmaxf(acc[2] + bb.z, 0.f));
        o[3] = f2b(fmaxf(acc[3] + bb.w, 0.f));
        *(short4v*)(&H[rl][wt * 16 + quad * 4]) = o;
    }
    __syncthreads();                      // done reading W1a
    stage32k<9>(W1b + 16384, Wlds, t);    // W1 rows 64..127
    __syncthreads();

    // ---- phase 2b: hidden cols 64..127 ----
#pragma unroll
    for (int wt = 4; wt < 8; wt++) {
        floatx4 acc = {0.f, 0.f, 0.f, 0.f};
        int rb = (wt - 4) * 16 + m;
#pragma unroll
        for (int ks = 0; ks < 4; ks++) {
            short8 w = ldsW9(Wlds, (rb << 9) + (ks << 6) + (quad << 4));
            acc = MFMA(w, c4[ks], acc);
        }
#pragma unroll
        for (int ks = 0; ks < 4; ks++) {
            short8 w = ldsW9(Wlds, (rb << 9) + 256 + (ks << 6) + (quad << 4));
            acc = MFMA(w, ar[ks], acc);
        }
        float4 bb = *(const float4*)(b1 + wt * 16 + quad * 4);
        short4v o;
        o[0] = f2b(fmaxf(acc[0] + bb.x, 0.f));
        o[1] = f2b(fmaxf(acc[1] + bb.y, 0.f));
        o[2] = f2b(fmaxf(acc[2] + bb.z, 0.f));
        o[3] = f2b(fmaxf(acc[3] + bb.w, 0.f));
        *(short4v*)(&H[rl][wt * 16 + quad * 4]) = o;
    }
    short8 h4[4];
#pragma unroll
    for (int ks = 0; ks < 4; ks++)
        h4[ks] = *(const short8*)(&H[rl][ks * 32 + quad * 8]);
    __syncthreads();                      // done reading W1b
    stage32k<8>(W2b, Wlds, t);
    __syncthreads();

    // ---- phase 3: out = hidden @ W2^T + b2 (coalesced float4 stores) ----
#pragma unroll
    for (int wt = 0; wt < 8; wt++) {
        floatx4 acc = {0.f, 0.f, 0.f, 0.f};
#pragma unroll
        for (int ks = 0; ks < 4; ks++) {
            short8 w = ldsW8(Wlds, ((wt * 16 + m) << 8) + (ks << 6) + (quad << 4));
            acc = MFMA(w, h4[ks], acc);
        }
        if (ok) {
            float4 bb = *(const float4*)(b2 + wt * 16 + quad * 4);
            float4 o;
            o.x = acc[0] + bb.x;
            o.y = acc[1] + bb.y;
            o.z = acc[2] + bb.z;
            o.w = acc[3] + bb.w;
            *(float4*)(out + xrow * EMB + wt * 16 + quad * 4) = o;
        }
    }
}

// ---------------------------------------------------------------------------
extern "C" void kernel_launch(void* const* d_in, const int* in_sizes, int n_in,
                              void* d_out, int out_size, void* d_ws, size_t ws_size,
                              hipStream_t stream) {
    const float* left   = (const float*)d_in[0];
    const int*   eidx   = (const int*)  d_in[1];
    const float* efeat  = (const float*)d_in[2];
    const float* right  = (const float*)d_in[3];
    const float* W_left = (const float*)d_in[5];
    const float* b_left = (const float*)d_in[6];
    const float* W_edge = (const float*)d_in[7];
    const float* W_right= (const float*)d_in[8];
    const float* sc_fin = (const float*)d_in[9];
    const float* W_fin  = (const float*)d_in[10];
    const float* b_fin  = (const float*)d_in[11];
    const float* sc_post= (const float*)d_in[12];
    const float* W_out1 = (const float*)d_in[13];
    const float* b_out1 = (const float*)d_in[14];
    const float* W_out2 = (const float*)d_in[15];
    const float* b_out2 = (const float*)d_in[16];

    int n_left  = in_sizes[0] / EMB;        // 100000
    int n_edges = in_sizes[2];              // 600000
    int n_right = in_sizes[3] / EMB;        // 100000

    ushort* us = (ushort*)d_ws;
    ushort* Wl_b = us;                       // packed bf16 weights
    ushort* Wr_b = us + 16384;
    ushort* Wf_b = us + 32768;
    ushort* W1_b = us + 49152;
    ushort* W2_b = us + 81920;
    ushort* Pl   = us + 98304;               // n_left*128
    ushort* Pr   = Pl + (size_t)n_left * EMB;
    ushort* S    = Pr + (size_t)n_right * EMB;
    int* cnt    = (int*)(S + (size_t)n_right * EMB);
    int* offs   = cnt + n_right;
    int* cursor = offs + n_right;
    int* bsum   = cursor + n_right;
    int2* sle   = (int2*)(bsum + 64);

    hipMemsetAsync(cnt, 0, (size_t)n_right * sizeof(int), stream);

    int eb = (n_edges + 255) / 256;          // 2344
    int nsb = (n_right + SCAN_CHUNK - 1) / SCAN_CHUNK;   // 25

    // weights->bf16 + degree histogram (independent, one launch)
    k_cvthist<<<384 + eb, 256, 0, stream>>>(W_left, W_right, W_fin, W_out1,
                                            W_out2, us, eidx, cnt, n_edges);

    // exclusive scan of degrees
    k_scan1<<<nsb, 1024, 0, stream>>>(cnt, offs, bsum, n_right);
    k_scan2<<<nsb, 1024, 0, stream>>>(bsum, offs, cursor, n_right);

    // sorted edge list + both projections (persistent proj blocks)
    k_permproj<<<eb + 2 * PROJ_PB, 256, 0, stream>>>(eidx, efeat, cursor, sle,
                                                     n_edges, left, right,
                                                     Wl_b, Wr_b, b_left,
                                                     Pl, Pr, n_left, eb);

    // segmented reduction -> S (one wave per right node, 4-wide gather)
    k_reduce<<<(n_right + 3) / 4, 256, 0, stream>>>(Pl, Pr, sle, W_edge, offs,
                                                    sc_fin, S, n_right, n_edges);

    // conv GEMM + output MLP (LDS-staged weights)
    k_out<<<(n_right + 63) / 64, 256, 0, stream>>>(S, right, Wf_b, b_fin,
                                                   cnt, sc_post, W1_b, b_out1,
                                                   W2_b, b_out2,
                                                   (float*)d_out, n_right);
}